// Round 16
// baseline (310.546 us; speedup 1.0000x reference)
//
#include <hip/hip_runtime.h>
#include <cstdint>
#include <cstddef>

using u32 = unsigned int;
using u64 = unsigned long long;

typedef int v4i  __attribute__((ext_vector_type(4)));
typedef int v16i __attribute__((ext_vector_type(16)));

#define EPSV 1e-5f
#define MFMA_I8(A, B, C) __builtin_amdgcn_mfma_i32_32x32x32_i8((A), (B), (C), 0, 0, 0)

// ---------------------------------------------------------------------------
// Kernel 1: weight prep. Wsgn[conv][co][p][c] = sign(w - mean);
// SC4 = (alpha, scale, shift, 0), IEEE ops in the reference's exact order.
// ---------------------------------------------------------------------------
__global__ void prep_weights(const float* __restrict__ w1, const float* __restrict__ w2,
                             const float* __restrict__ a1, const float* __restrict__ g1,
                             const float* __restrict__ b1, const float* __restrict__ m1,
                             const float* __restrict__ v1,
                             const float* __restrict__ a2, const float* __restrict__ g2,
                             const float* __restrict__ b2, const float* __restrict__ m2,
                             const float* __restrict__ v2,
                             unsigned char* __restrict__ Wsgn, float4* __restrict__ SC4)
{
    const int co   = blockIdx.x;
    const int conv = blockIdx.y;
    const int c    = threadIdx.x;
    const float* w = conv ? w2 : w1;

    float wv[9];
    const float* wp = w + ((size_t)co * 256 + c) * 9;
    float s = 0.f;
#pragma unroll
    for (int p = 0; p < 9; ++p) { wv[p] = wp[p]; s += wv[p]; }

    __shared__ float red[256];
    red[c] = s;
    __syncthreads();
    for (int off = 128; off > 0; off >>= 1) {
        if (c < off) red[c] += red[c + off];
        __syncthreads();
    }
    const float mean = __fdiv_rn(red[0], 2304.0f);

    unsigned char* wrow = Wsgn + ((size_t)(conv * 256 + co) * 9) * 256;
#pragma unroll
    for (int p = 0; p < 9; ++p)
        wrow[p * 256 + c] = (wv[p] > mean) ? 0x01u : 0xFFu;

    if (c == 0) {
        const float alpha = conv ? a2[co] : a1[co];
        const float gamma = conv ? g2[co] : g1[co];
        const float beta  = conv ? b2[co] : b1[co];
        const float mu    = conv ? m2[co] : m1[co];
        const float var   = conv ? v2[co] : v1[co];
        const float sq    = __fsqrt_rn(__fadd_rn(var, EPSV));
        const float scale = __fdiv_rn(gamma, sq);
        const float shift = __fsub_rn(beta, __fdiv_rn(__fmul_rn(mu, gamma), sq));
        SC4[conv * 256 + co] = make_float4(alpha, scale, shift, 0.f);
    }
}

// ---------------------------------------------------------------------------
// Kernel 2: B fragments in exact mfma_i32_32x32x32_i8 operand order.
// Frag f = conv*576 + g*72 + k. Lane l: B[k=(l>>5)*16+j][n=l&31].
// ---------------------------------------------------------------------------
__global__ void build_bfrag(const unsigned char* __restrict__ Wsgn, uint4* __restrict__ Bf)
{
    const int f    = blockIdx.x;           // 0..1151
    const int lane = threadIdx.x;          // 0..63
    const int conv = f / 576;
    const int rem  = f % 576;
    const int g    = rem / 72;
    const int p    = (rem % 72) / 8;
    const int cb   = rem % 8;
    const int co   = g * 32 + (lane & 31);
    const unsigned char* src = Wsgn + ((size_t)(conv * 256 + co) * 9 + p) * 256
                                    + cb * 32 + (lane >> 5) * 16;
    Bf[(size_t)f * 64 + lane] = *(const uint4*)src;
}

// ---------------------------------------------------------------------------
// Kernel 3: binarize x -> packed bits. A[n][pixel][j], j = chan/32.
// ---------------------------------------------------------------------------
__global__ void binarize_x(const float* __restrict__ x, u32* __restrict__ A1)
{
    const int n = blockIdx.x >> 3;
    const int j = blockIdx.x & 7;
    const int p = threadIdx.x;
    const float* xp = x + (((size_t)n * 256 + j * 32) * 1024) + p;
    u32 bits = 0;
#pragma unroll
    for (int k = 0; k < 32; ++k) {
        float v = xp[(size_t)k * 1024];
        bits |= (v > 0.f ? 1u : 0u) << k;
    }
    A1[((size_t)n * 1024 + p) * 8 + j] = bits;
}

__device__ __forceinline__ u32 expand4(u32 x)
{
    u32 r;
    r  = ((x & 1u) ? 0x00000001u : 0x000000FFu);
    r |= ((x & 2u) ? 0x00000100u : 0x0000FF00u);
    r |= ((x & 4u) ? 0x00010000u : 0x00FF0000u);
    r |= ((x & 8u) ? 0x01000000u : 0xFF000000u);
    return r;
}

__device__ __forceinline__ void glds16(const void* g, void* l)
{
    __builtin_amdgcn_global_load_lds(
        (const __attribute__((address_space(1))) void*)g,
        (__attribute__((address_space(3))) void*)l, 16, 0, 0);
}

// ---------------------------------------------------------------------------
// Kernel 4/5: binary conv as i8 MFMA GEMM — 1-wave/SIMD interleaved issue.
//
// R5-R15 post-mortem (7 schedules, all MfmaUtil 20-25%): per-CU cycle audit
// shows MFMA 42k + VALU 35k + LDS 29k + waits ≈ measured 160k — the pipes
// run SERIALLY. Cause: in-order wave issue. MFMA clusters stall the wave on
// matrix-pipe availability (1 MFMA/~36cyc/SIMD), mem/VALU behind the cluster
// can't issue in the gaps; SIMD-mate waves phase-lock and stall together.
//
// Fix: ONE wave per SIMD feeding every pipe itself via source interleave:
//   per step: [lgkm(0)] [addrs + 4 glds(B,k+3)] then 8x{1 ds_read(k+1 set);
//   2 MFMA(k set)} with sched_barrier(0) pinning each chunk; vmcnt(8)
//   (counted, 2-step glds cover) before the B reads. MFMA:ds = 16:8.
//
// Block: 256 thr = 4 waves; wave (wm=w>>1, wn=w&1) owns rows y0+4wm..+3 x
// groups wn*4..+3 -> 16 v16i accs (256 AGPR). Block = 8 rows x 256 cos.
// Grid 256 = 1 block/CU (LDS 152,576 forces it).
// LDS: A [c16 16][row 10][col 34] 16B cells, halo zeroed = 87,040;
//      B rings at 87,040 + wave*16,384: 4 slots x 4KB (4 groups x 1KB).
// A: m(=x)=l&31, k=(l>>5)*16+j ; B: n(=co)=l&31 ; C/D: n=l&31,
// m=(reg&3)+8*(reg>>2)+4*(l>>5)   [R5-R15 HW-verified].
//
// CONV==1: t=(dot*alpha)*scale+shift; packed sign bits via __ballot.
// CONV==2: per-row LDS transpose ep[x][co] (pad 257) -> coalesced
//          clamp(t + X) float4 stores.
// ---------------------------------------------------------------------------
template<int CONV>
__global__ __launch_bounds__(256, 1)
void conv_mfma(const u32* __restrict__ A_in, const v4i* __restrict__ Bf,
               const float4* __restrict__ SC4, const float* __restrict__ X,
               u32* __restrict__ A_out, float* __restrict__ OUT)
{
    const int n    = blockIdx.x >> 2;
    const int yo   = blockIdx.x & 3;
    const int y0   = yo * 8;
    const int tid  = threadIdx.x;
    const int wave = tid >> 6;          // 0..3
    const int lane = tid & 63;
    const int wm   = wave >> 1;         // rows y0+4wm .. +3
    const int wn   = wave & 1;          // groups wn*4 .. +3
    const int col0 = lane & 31;
    const int g0   = wn * 4;

    __shared__ alignas(16) unsigned char lds[152576];

    const int fbias = (CONV == 2) ? 576 : 0;
    const char* bs0 = (const char*)Bf + (((size_t)(fbias + (g0 + 0) * 72)) << 10) + (size_t)lane * 16;
    const char* bs1 = (const char*)Bf + (((size_t)(fbias + (g0 + 1) * 72)) << 10) + (size_t)lane * 16;
    const char* bs2 = (const char*)Bf + (((size_t)(fbias + (g0 + 2) * 72)) << 10) + (size_t)lane * 16;
    const char* bs3 = (const char*)Bf + (((size_t)(fbias + (g0 + 3) * 72)) << 10) + (size_t)lane * 16;
    unsigned char* bdst = lds + 87040 + (size_t)wave * 16384;

    // prologue: stage B steps 0,1,2 -> slots 0,1,2 (12 glds)
#pragma unroll
    for (int s = 0; s < 3; ++s) {
        unsigned char* d = bdst + s * 4096;
        glds16(bs0 + ((size_t)s << 10), d);
        glds16(bs1 + ((size_t)s << 10), d + 1024);
        glds16(bs2 + ((size_t)s << 10), d + 2048);
        glds16(bs3 + ((size_t)s << 10), d + 3072);
    }

    // stage A tile [c16][row 0..9][col 0..33], halo (row/col OOB) -> 0
    for (int s = tid; s < 5440; s += 256) {
        const int colv = s % 34;
        const int rest = s / 34;
        const int r    = rest % 10;
        const int c16  = rest / 10;
        const int iy   = y0 - 1 + r;
        const int ix   = colv - 1;
        u32 d0 = 0, d1 = 0, d2 = 0, d3 = 0;
        if ((unsigned)iy < 32u && (unsigned)ix < 32u) {
            const u32 wrd = A_in[((size_t)n * 1024 + iy * 32 + ix) * 8 + (c16 >> 1)];
            const u32 h = (wrd >> ((c16 & 1) * 16)) & 0xFFFFu;
            d0 = expand4(h);
            d1 = expand4(h >> 4);
            d2 = expand4(h >> 8);
            d3 = expand4(h >> 12);
        }
        *(uint4*)(lds + (size_t)s * 16) = make_uint4(d0, d1, d2, d3);
    }

    const int bias2 = (CONV == 2) ? 256 : 0;
    const float4 scA = SC4[bias2 + (g0 + 0) * 32 + col0];
    const float4 scB = SC4[bias2 + (g0 + 1) * 32 + col0];
    const float4 scC = SC4[bias2 + (g0 + 2) * 32 + col0];
    const float4 scD = SC4[bias2 + (g0 + 3) * 32 + col0];

    __syncthreads();   // A tile visible; all prologue vm/lgkm drained

    const v16i Z  = {0,0,0,0,0,0,0,0,0,0,0,0,0,0,0,0};
    v16i c00 = Z, c01 = Z, c02 = Z, c03 = Z;   // row 4wm+0 x groups 0..3
    v16i c10 = Z, c11 = Z, c12 = Z, c13 = Z;
    v16i c20 = Z, c21 = Z, c22 = Z, c23 = Z;
    v16i c30 = Z, c31 = Z, c32 = Z, c33 = Z;

    const u32 lhalf = (u32)((lane >> 5) * 5440);
    const u32 bb    = 87040u + (u32)(wave * 16384 + lane * 16);

    // preload E with step 0 (cb=0, dy=0, dx=0)
    v4i ea0, ea1, ea2, ea3, eb0, eb1, eb2, eb3;
    v4i oa0, oa1, oa2, oa3, ob0, ob1, ob2, ob3;
    {
        const u32 ao = (lhalf + (u32)((4 * wm) * 544 + col0 * 16)) * 16u / 16u;
        ea0 = *(const v4i*)(lds + ao);
        ea1 = *(const v4i*)(lds + ao + 544 * 16 / 16 * 1 + 544 - 544 + 544);   // +544
        ea1 = *(const v4i*)(lds + ao + 544);
        ea2 = *(const v4i*)(lds + ao + 1088);
        ea3 = *(const v4i*)(lds + ao + 1632);
        eb0 = *(const v4i*)(lds + bb);
        eb1 = *(const v4i*)(lds + bb + 1024);
        eb2 = *(const v4i*)(lds + bb + 2048);
        eb3 = *(const v4i*)(lds + bb + 3072);
    }

#define SB __builtin_amdgcn_sched_barrier(0)

#define STEP(KC, A0,A1,A2,A3, B0,B1,B2,B3, NA0,NA1,NA2,NA3, NB0,NB1,NB2,NB3)    \
    {                                                                           \
        const int k_ = (KC);                                                    \
        asm volatile("s_waitcnt lgkmcnt(0)" ::: "memory");                      \
        SB;                                                                     \
        {   /* glds batch for step k+3 (wrap harmless: re-stages early frag) */ \
            int kg = k_ + 3; if (kg >= 72) kg -= 72;                            \
            unsigned char* d_ = bdst + ((k_ + 3) & 3) * 4096;                   \
            glds16(bs0 + ((size_t)kg << 10), d_);                               \
            glds16(bs1 + ((size_t)kg << 10), d_ + 1024);                        \
            glds16(bs2 + ((size_t)kg << 10), d_ + 2048);                        \
            glds16(bs3 + ((size_t)kg << 10), d_ + 3072);                        \
        }                                                                       \
        SB;                                                                     \
        const int kn_ = k_ + 1;                                                 \
        const int cbn_ = kn_ & 7, pn_ = kn_ >> 3;                               \
        const int dyn_ = (pn_ * 11) >> 5;                                       \
        const int dxn_ = pn_ - dyn_ * 3;                                        \
        const u32 aon_ = lhalf + (u32)(cbn_ * 10880)                            \
                       + (u32)((4 * wm + dyn_) * 544)                          \
                       + (u32)((col0 + dxn_) * 16);                            \
        const u32 bon_ = bb + (u32)((kn_ & 3) * 4096);                          \
        NA0 = *(const v4i*)(lds + aon_);                                        \
        c00 = MFMA_I8(A0, B0, c00);  c01 = MFMA_I8(A0, B1, c01);  SB;           \
        NA1 = *(const v4i*)(lds + aon_ + 544);                                  \
        c02 = MFMA_I8(A0, B2, c02);  c03 = MFMA_I8(A0, B3, c03);  SB;           \
        NA2 = *(const v4i*)(lds + aon_ + 1088);                                 \
        c10 = MFMA_I8(A1, B0, c10);  c11 = MFMA_I8(A1, B1, c11);  SB;           \
        NA3 = *(const v4i*)(lds + aon_ + 1632);                                 \
        c12 = MFMA_I8(A1, B2, c12);  c13 = MFMA_I8(A1, B3, c13);  SB;           \
        asm volatile("s_waitcnt vmcnt(8)" ::: "memory");                        \
        SB;                                                                     \
        NB0 = *(const v4i*)(lds + bon_);                                        \
        c20 = MFMA_I8(A2, B0, c20);  c21 = MFMA_I8(A2, B1, c21);  SB;           \
        NB1 = *(const v4i*)(lds + bon_ + 1024);                                 \
        c22 = MFMA_I8(A2, B2, c22);  c23 = MFMA_I8(A2, B3, c23);  SB;           \
        NB2 = *(const v4i*)(lds + bon_ + 2048);                                 \
        c30 = MFMA_I8(A3, B0, c30);  c31 = MFMA_I8(A3, B1, c31);  SB;           \
        NB3 = *(const v4i*)(lds + bon_ + 3072);                                 \
        c32 = MFMA_I8(A3, B2, c32);  c33 = MFMA_I8(A3, B3, c33);  SB;           \
    }

#pragma unroll 1
    for (int j = 0; j < 36; ++j) {
        const int k = j * 2;
        STEP(k,     ea0,ea1,ea2,ea3, eb0,eb1,eb2,eb3,
                    oa0,oa1,oa2,oa3, ob0,ob1,ob2,ob3)
        STEP(k + 1, oa0,oa1,oa2,oa3, ob0,ob1,ob2,ob3,
                    ea0,ea1,ea2,ea3, eb0,eb1,eb2,eb3)
    }
#undef STEP
#undef SB

    if (CONV == 1) {
#define EP1(ACC, RI, GI, SC)                                                    \
        { _Pragma("unroll")                                                     \
          for (int reg = 0; reg < 16; ++reg) {                                  \
              const float t = __fadd_rn(__fmul_rn(__fmul_rn((float)ACC[reg],    \
                                        SC.x), SC.y), SC.z);                    \
              const u64 m = __ballot(t > 0.f);                                  \
              if (lane == 0) {                                                  \
                  const int x = (reg & 3) + 8 * (reg >> 2);                     \
                  const int row = y0 + 4 * wm + (RI);                           \
                  const size_t pb = (size_t)n * 1024 + row * 32 + x;            \
                  A_out[pb * 8 + (g0 + (GI))]       = (u32)m;                   \
                  A_out[(pb + 4) * 8 + (g0 + (GI))] = (u32)(m >> 32);           \
              } } }
        EP1(c00, 0, 0, scA)  EP1(c01, 0, 1, scB)  EP1(c02, 0, 2, scC)  EP1(c03, 0, 3, scD)
        EP1(c10, 1, 0, scA)  EP1(c11, 1, 1, scB)  EP1(c12, 1, 2, scC)  EP1(c13, 1, 3, scD)
        EP1(c20, 2, 0, scA)  EP1(c21, 2, 1, scB)  EP1(c22, 2, 2, scC)  EP1(c23, 2, 3, scD)
        EP1(c30, 3, 0, scA)  EP1(c31, 3, 1, scB)  EP1(c32, 3, 2, scC)  EP1(c33, 3, 3, scD)
#undef EP1
    } else {
        __syncthreads();
        float* ep = (float*)lds;            // ep[x][co], stride 257 (32.9 KB)
#define EP2PASS(CA, CB, CC, CD, R)                                              \
        { if (wm == ((R) >> 2)) {                                               \
            _Pragma("unroll")                                                   \
            for (int reg = 0; reg < 16; ++reg) {                                \
                const int x = (reg & 3) + 8 * (reg >> 2) + 4 * (lane >> 5);     \
                ep[x * 257 + (g0 + 0) * 32 + col0] =                            \
                    __fadd_rn(__fmul_rn(__fmul_rn((float)CA[reg], scA.x),       \
                                        scA.y), scA.z);                         \
                ep[x * 257 + (g0 + 1) * 32 + col0] =                            \
                    __fadd_rn(__fmul_rn(__fmul_rn((float)CB[reg], scB.x),       \
                                        scB.y), scB.z);                         \
                ep[x * 257 + (g0 + 2) * 32 + col0] =                            \
                    __fadd_rn(__fmul_rn(__fmul_rn((float)CC[reg], scC.x),       \
                                        scC.y), scC.z);                         \
                ep[x * 257 + (g0 + 3) * 32 + col0] =                            \
                    __fadd_rn(__fmul_rn(__fmul_rn((float)CD[reg], scD.x),       \
                                        scD.y), scD.z);                         \
            } }                                                                 \
          __syncthreads();                                                      \
          {                                                                     \
              const int co = tid;                                               \
              const size_t gb = ((size_t)(n * 256 + co)) * 1024                 \
                              + (y0 + (R)) * 32;                                \
              _Pragma("unroll")                                                 \
              for (int x4 = 0; x4 < 32; x4 += 4) {                              \
                  float4 rr;                                                    \
                  rr.x = ep[(x4 + 0) * 257 + co];                               \
                  rr.y = ep[(x4 + 1) * 257 + co];                               \
                  rr.z = ep[(x4 + 2) * 257 + co];                               \
                  rr.w = ep[(x4 + 3) * 257 + co];                               \
                  const float4 xv = *(const float4*)(X + gb + x4);              \
                  rr.x = fminf(1.f, fmaxf(-1.f, __fadd_rn(rr.x, xv.x)));        \
                  rr.y = fminf(1.f, fmaxf(-1.f, __fadd_rn(rr.y, xv.y)));        \
                  rr.z = fminf(1.f, fmaxf(-1.f, __fadd_rn(rr.z, xv.z)));        \
                  rr.w = fminf(1.f, fmaxf(-1.f, __fadd_rn(rr.w, xv.w)));        \
                  *(float4*)(OUT + gb + x4) = rr;                               \
              }                                                                 \
          }                                                                     \
          __syncthreads(); }
        EP2PASS(c00, c01, c02, c03, 0)
        EP2PASS(c10, c11, c12, c13, 1)
        EP2PASS(c20, c21, c22, c23, 2)
        EP2PASS(c30, c31, c32, c33, 3)
        EP2PASS(c00, c01, c02, c03, 4)
        EP2PASS(c10, c11, c12, c13, 5)
        EP2PASS(c20, c21, c22, c23, 6)
        EP2PASS(c30, c31, c32, c33, 7)
#undef EP2PASS
    }
}

// ---------------------------------------------------------------------------
extern "C" void kernel_launch(void* const* d_in, const int* in_sizes, int n_in,
                              void* d_out, int out_size, void* d_ws, size_t ws_size,
                              hipStream_t stream)
{
    const float* x   = (const float*)d_in[0];
    const float* w1  = (const float*)d_in[1];
    const float* al1 = (const float*)d_in[2];
    const float* g1  = (const float*)d_in[3];
    const float* b1  = (const float*)d_in[4];
    const float* m1  = (const float*)d_in[5];
    const float* v1  = (const float*)d_in[6];
    const float* w2  = (const float*)d_in[7];
    const float* al2 = (const float*)d_in[8];
    const float* g2  = (const float*)d_in[9];
    const float* b2  = (const float*)d_in[10];
    const float* m2  = (const float*)d_in[11];
    const float* v2  = (const float*)d_in[12];
    float* out = (float*)d_out;

    char* ws = (char*)d_ws;
    float4*        SC4  = (float4*)(ws);                        //   8 KB
    unsigned char* Wsgn = (unsigned char*)(ws + (64u << 10));   // 1.18 MB
    uint4*         Bf   = (uint4*)(ws + (2u << 20));            // 1.18 MB
    u32*           A1   = (u32*)(ws + (4u << 20));              // 2 MB
    u32*           A2   = (u32*)(ws + (6u << 20));              // 2 MB
    (void)ws_size; (void)in_sizes; (void)n_in; (void)out_size;

    prep_weights<<<dim3(256, 2), 256, 0, stream>>>(w1, w2, al1, g1, b1, m1, v1,
                                                   al2, g2, b2, m2, v2, Wsgn, SC4);
    build_bfrag<<<dim3(1152), 64, 0, stream>>>(Wsgn, Bf);
    binarize_x<<<dim3(512), 1024, 0, stream>>>(x, A1);
    conv_mfma<1><<<dim3(256), 256, 0, stream>>>(A1, (const v4i*)Bf, SC4,
                                                nullptr, A2, nullptr);
    conv_mfma<2><<<dim3(256), 256, 0, stream>>>(A2, (const v4i*)Bf, SC4,
                                                x, nullptr, out);
}

// Round 17
// 138.367 us; speedup vs baseline: 2.2444x; 2.2444x over previous
//
#include <hip/hip_runtime.h>
#include <cstdint>
#include <cstddef>

using u32 = unsigned int;
using u64 = unsigned long long;

typedef int v4i  __attribute__((ext_vector_type(4)));
typedef int v16i __attribute__((ext_vector_type(16)));

#define EPSV 1e-5f

// ---------------------------------------------------------------------------
// Kernel 1: weight prep. One block per (co, conv). 256 threads = 256 in-chans.
// Wsgn[conv][co][p][c] i8 = sign(w - mean); SC4 = (alpha, scale, shift, 0)
// with IEEE ops in the reference's exact order.
// ---------------------------------------------------------------------------
__global__ void prep_weights(const float* __restrict__ w1, const float* __restrict__ w2,
                             const float* __restrict__ a1, const float* __restrict__ g1,
                             const float* __restrict__ b1, const float* __restrict__ m1,
                             const float* __restrict__ v1,
                             const float* __restrict__ a2, const float* __restrict__ g2,
                             const float* __restrict__ b2, const float* __restrict__ m2,
                             const float* __restrict__ v2,
                             unsigned char* __restrict__ Wsgn, float4* __restrict__ SC4)
{
    const int co   = blockIdx.x;
    const int conv = blockIdx.y;
    const int c    = threadIdx.x;
    const float* w = conv ? w2 : w1;

    float wv[9];
    const float* wp = w + ((size_t)co * 256 + c) * 9;
    float s = 0.f;
#pragma unroll
    for (int p = 0; p < 9; ++p) { wv[p] = wp[p]; s += wv[p]; }

    __shared__ float red[256];
    red[c] = s;
    __syncthreads();
    for (int off = 128; off > 0; off >>= 1) {
        if (c < off) red[c] += red[c + off];
        __syncthreads();
    }
    const float mean = __fdiv_rn(red[0], 2304.0f);

    unsigned char* wrow = Wsgn + ((size_t)(conv * 256 + co) * 9) * 256;
#pragma unroll
    for (int p = 0; p < 9; ++p)
        wrow[p * 256 + c] = (wv[p] > mean) ? 0x01u : 0xFFu;

    if (c == 0) {
        const float alpha = conv ? a2[co] : a1[co];
        const float gamma = conv ? g2[co] : g1[co];
        const float beta  = conv ? b2[co] : b1[co];
        const float mu    = conv ? m2[co] : m1[co];
        const float var   = conv ? v2[co] : v1[co];
        const float sq    = __fsqrt_rn(__fadd_rn(var, EPSV));
        const float scale = __fdiv_rn(gamma, sq);
        const float shift = __fsub_rn(beta, __fdiv_rn(__fmul_rn(mu, gamma), sq));
        SC4[conv * 256 + co] = make_float4(alpha, scale, shift, 0.f);
    }
}

// ---------------------------------------------------------------------------
// Kernel 2: B fragments in exact mfma_i32_32x32x32_i8 operand order.
// Frag f = conv*576 + g*72 + p*8 + cb. Lane l: B[k=(l>>5)*16+j][n=l&31].
// ---------------------------------------------------------------------------
__global__ void build_bfrag(const unsigned char* __restrict__ Wsgn, uint4* __restrict__ Bf)
{
    const int f    = blockIdx.x;           // 0..1151
    const int lane = threadIdx.x;          // 0..63
    const int conv = f / 576;
    const int rem  = f % 576;
    const int g    = rem / 72;
    const int p    = (rem % 72) / 8;
    const int cb   = rem % 8;
    const int co   = g * 32 + (lane & 31);
    const unsigned char* src = Wsgn + ((size_t)(conv * 256 + co) * 9 + p) * 256
                                    + cb * 32 + (lane >> 5) * 16;
    Bf[(size_t)f * 64 + lane] = *(const uint4*)src;
}

// ---------------------------------------------------------------------------
// Kernel 3: binarize x -> packed bits. A[n][pixel][j], j = chan/32.
// ---------------------------------------------------------------------------
__global__ void binarize_x(const float* __restrict__ x, u32* __restrict__ A1)
{
    const int n = blockIdx.x >> 3;
    const int j = blockIdx.x & 7;
    const int p = threadIdx.x;
    const float* xp = x + (((size_t)n * 256 + j * 32) * 1024) + p;
    u32 bits = 0;
#pragma unroll
    for (int k = 0; k < 32; ++k) {
        float v = xp[(size_t)k * 1024];
        bits |= (v > 0.f ? 1u : 0u) << k;
    }
    A1[((size_t)n * 1024 + p) * 8 + j] = bits;
}

__device__ __forceinline__ u32 expand4(u32 x)
{
    u32 r;
    r  = ((x & 1u) ? 0x00000001u : 0x000000FFu);
    r |= ((x & 2u) ? 0x00000100u : 0x0000FF00u);
    r |= ((x & 4u) ? 0x00010000u : 0x00FF0000u);
    r |= ((x & 8u) ? 0x01000000u : 0xFF000000u);
    return r;
}

// ---------------------------------------------------------------------------
// Kernel 4/5: binary conv as i8 MFMA GEMM — R8 structure at 4 blocks/CU.
// Block: 256 thr = 4 waves. Covers 2 output rows x 32 cols x ALL 256 cos.
// Wave w: co-groups g0=2w, g1=2w+1, rows y0,y0+1 -> 4 v16i accumulators.
// Grid: 64 n x 16 ypairs = 1024 blocks = 4 blocks/CU (LDS 4x34,816=139KB).
//
// R17 experiment: ONE variable vs R8 — __launch_bounds__(256,4) instead of
// (256,3). R8's footprint (56 VGPR + 64 AGPR = 120 <= 128) exactly fits
// 4 waves/SIMD. Hypothesis (Guideline 1): the ~50us of per-wave exposed
// load latency that 8 ILP schedules failed to hide DOES interleave across
// 16 concurrent waves/CU. The K-loop is barrier-free per-wave, so waves
// drift and fill each other's stall gaps.
//
// LDS act tile [c16 0..15][r 0..3][xs 0..33], 16B cells. granule%8 = xs%8
// -> ds_read_b128 conflict-free (R6-R15 verified: SQ_LDS_BANK_CONFLICT=0).
// Per iteration (rolled, unroll 1): 4 B-loads + 4 ds_read_b128 + 8 mfma,
// bounded liveness (no spill at 56 VGPR — R8-verified).
//
// A: m(=x)=l&31, k=(l>>5)*16+j ; B: n(=co)=l&31 ; C/D: n=l&31,
// m=(reg&3)+8*(reg>>2)+4*(l>>5)   [R5-R15 HW-verified].
//
// CONV==1: t=(dot*alpha)*scale+shift; packed sign bits via __ballot.
// CONV==2: per-row LDS transpose ep[x][co] (pad 257) -> coalesced
//          clamp(t + X) float4 stores.
// ---------------------------------------------------------------------------
template<int CONV>
__global__ __launch_bounds__(256, 4)
void conv_mfma(const u32* __restrict__ A_in, const v4i* __restrict__ Bf,
               const float4* __restrict__ SC4, const float* __restrict__ X,
               u32* __restrict__ A_out, float* __restrict__ OUT)
{
    const int n    = blockIdx.x >> 4;
    const int yp   = blockIdx.x & 15;
    const int y0   = yp * 2;
    const int tid  = threadIdx.x;
    const int wave = tid >> 6;
    const int lane = tid & 63;

    __shared__ alignas(16) unsigned char lds[34816];

    // ---- stage: packed bits -> i8 tile [c16][r][xs], halo -> 0 ----
    for (int s = tid; s < 2176; s += 256) {
        const int xs   = s % 34;
        const int rest = s / 34;
        const int r    = rest & 3;          // tile row (image row y0-1+r)
        const int c16  = rest >> 2;         // 16-channel group
        const int iy   = y0 - 1 + r;
        const int ix   = xs - 1;
        u32 d0 = 0, d1 = 0, d2 = 0, d3 = 0;
        if ((unsigned)iy < 32u && (unsigned)ix < 32u) {
            const u32 wrd = A_in[((size_t)n * 1024 + iy * 32 + ix) * 8 + (c16 >> 1)];
            const u32 h = (wrd >> ((c16 & 1) * 16)) & 0xFFFFu;
            d0 = expand4(h);
            d1 = expand4(h >> 4);
            d2 = expand4(h >> 8);
            d3 = expand4(h >> 12);
        }
        *(uint4*)(lds + (size_t)s * 16) = make_uint4(d0, d1, d2, d3);
    }
    __syncthreads();

    // ---- K-loop: rolled, 36 iterations x (4 loads + 4 ds_read + 8 mfma) ----
    const v16i Z = {0,0,0,0,0,0,0,0,0,0,0,0,0,0,0,0};
    v16i acc00 = Z, acc01 = Z;   // row y0   x {g0, g1}
    v16i acc10 = Z, acc11 = Z;   // row y0+1 x {g0, g1}

    const int g0 = wave * 2, g1 = g0 + 1;
    const v4i* bp0 = Bf + ((size_t)(((CONV == 2) ? 576 : 0) + g0 * 72)) * 64 + lane;
    const v4i* bp1 = Bf + ((size_t)(((CONV == 2) ? 576 : 0) + g1 * 72)) * 64 + lane;
    const u32 labase = (u32)((lane >> 5) * 2176 + (lane & 31) * 16);

    u32 rowoff = labase;
#pragma unroll 1
    for (int dy = 0; dy < 3; ++dy) {
        u32 ob = rowoff;
#pragma unroll 1
        for (int dx = 0; dx < 3; ++dx) {
            u32 dso = ob;
#pragma unroll 1
            for (int cbp = 0; cbp < 4; ++cbp) {
                const v4i b0a = bp0[0];
                const v4i b0b = bp0[64];
                const v4i b1a = bp1[0];
                const v4i b1b = bp1[64];
                bp0 += 128;
                bp1 += 128;
                const v4i a0 = *(const v4i*)(lds + dso);           // even cb, row dy
                const v4i a1 = *(const v4i*)(lds + dso + 544);     // even cb, row dy+1
                const v4i a2 = *(const v4i*)(lds + dso + 4352);    // odd  cb, row dy
                const v4i a3 = *(const v4i*)(lds + dso + 4896);    // odd  cb, row dy+1
                dso += 8704;
                acc00 = __builtin_amdgcn_mfma_i32_32x32x32_i8(a0, b0a, acc00, 0, 0, 0);
                acc01 = __builtin_amdgcn_mfma_i32_32x32x32_i8(a0, b1a, acc01, 0, 0, 0);
                acc10 = __builtin_amdgcn_mfma_i32_32x32x32_i8(a1, b0a, acc10, 0, 0, 0);
                acc11 = __builtin_amdgcn_mfma_i32_32x32x32_i8(a1, b1a, acc11, 0, 0, 0);
                acc00 = __builtin_amdgcn_mfma_i32_32x32x32_i8(a2, b0b, acc00, 0, 0, 0);
                acc01 = __builtin_amdgcn_mfma_i32_32x32x32_i8(a2, b1b, acc01, 0, 0, 0);
                acc10 = __builtin_amdgcn_mfma_i32_32x32x32_i8(a3, b0b, acc10, 0, 0, 0);
                acc11 = __builtin_amdgcn_mfma_i32_32x32x32_i8(a3, b1b, acc11, 0, 0, 0);
            }
            ob += 16;
        }
        rowoff += 544;
    }

    const int col = lane & 31;
    const float4 sc0 = SC4[((CONV == 2) ? 256 : 0) + g0 * 32 + col];
    const float4 sc1 = SC4[((CONV == 2) ? 256 : 0) + g1 * 32 + col];

    if (CONV == 1) {
#define EP1(ACC, RY, G, SC)                                                     \
        { _Pragma("unroll")                                                     \
          for (int reg = 0; reg < 16; ++reg) {                                  \
              const float t = __fadd_rn(__fmul_rn(__fmul_rn((float)ACC[reg],    \
                                        SC.x), SC.y), SC.z);                    \
              const u64 m = __ballot(t > 0.f);                                  \
              if (lane == 0) {                                                  \
                  const int x = (reg & 3) + 8 * (reg >> 2);                     \
                  const size_t pb = (size_t)n * 1024 + (y0 + (RY)) * 32 + x;    \
                  A_out[pb * 8 + (G)]       = (u32)m;                           \
                  A_out[(pb + 4) * 8 + (G)] = (u32)(m >> 32);                   \
              } } }
        EP1(acc00, 0, g0, sc0)  EP1(acc01, 0, g1, sc1)
        EP1(acc10, 1, g0, sc0)  EP1(acc11, 1, g1, sc1)
#undef EP1
    } else {
        __syncthreads();                    // act tile reads done
        float* ep = (float*)lds;            // ep[x][co] pad 257 = 32.9 KB
#define EP2PASS(A0, A1, RY)                                                     \
        { _Pragma("unroll")                                                     \
          for (int reg = 0; reg < 16; ++reg) {                                  \
              const int x = (reg & 3) + 8 * (reg >> 2) + 4 * (lane >> 5);       \
              const float t0 = __fadd_rn(__fmul_rn(__fmul_rn((float)A0[reg],    \
                                         sc0.x), sc0.y), sc0.z);                \
              const float t1 = __fadd_rn(__fmul_rn(__fmul_rn((float)A1[reg],    \
                                         sc1.x), sc1.y), sc1.z);                \
              ep[x * 257 + g0 * 32 + col] = t0;                                 \
              ep[x * 257 + g1 * 32 + col] = t1;                                 \
          }                                                                     \
          __syncthreads();                                                      \
          {                                                                     \
              const int co = tid;                                               \
              const size_t gb = ((size_t)(n * 256 + co)) * 1024                 \
                              + (y0 + (RY)) * 32;                               \
              _Pragma("unroll")                                                 \
              for (int x4 = 0; x4 < 32; x4 += 4) {                              \
                  float4 r;                                                     \
                  r.x = ep[(x4 + 0) * 257 + co];                                \
                  r.y = ep[(x4 + 1) * 257 + co];                                \
                  r.z = ep[(x4 + 2) * 257 + co];                                \
                  r.w = ep[(x4 + 3) * 257 + co];                                \
                  const float4 xv = *(const float4*)(X + gb + x4);              \
                  r.x = fminf(1.f, fmaxf(-1.f, __fadd_rn(r.x, xv.x)));          \
                  r.y = fminf(1.f, fmaxf(-1.f, __fadd_rn(r.y, xv.y)));          \
                  r.z = fminf(1.f, fmaxf(-1.f, __fadd_rn(r.z, xv.z)));          \
                  r.w = fminf(1.f, fmaxf(-1.f, __fadd_rn(r.w, xv.w)));          \
                  *(float4*)(OUT + gb + x4) = r;                                \
              }                                                                 \
          }                                                                     \
          __syncthreads(); }
        EP2PASS(acc00, acc01, 0)
        EP2PASS(acc10, acc11, 1)
#undef EP2PASS
    }
}

// ---------------------------------------------------------------------------
extern "C" void kernel_launch(void* const* d_in, const int* in_sizes, int n_in,
                              void* d_out, int out_size, void* d_ws, size_t ws_size,
                              hipStream_t stream)
{
    const float* x   = (const float*)d_in[0];
    const float* w1  = (const float*)d_in[1];
    const float* al1 = (const float*)d_in[2];
    const float* g1  = (const float*)d_in[3];
    const float* b1  = (const float*)d_in[4];
    const float* m1  = (const float*)d_in[5];
    const float* v1  = (const float*)d_in[6];
    const float* w2  = (const float*)d_in[7];
    const float* al2 = (const float*)d_in[8];
    const float* g2  = (const float*)d_in[9];
    const float* b2  = (const float*)d_in[10];
    const float* m2  = (const float*)d_in[11];
    const float* v2  = (const float*)d_in[12];
    float* out = (float*)d_out;

    char* ws = (char*)d_ws;
    float4*        SC4  = (float4*)(ws);                        //   8 KB
    unsigned char* Wsgn = (unsigned char*)(ws + (64u << 10));   // 1.18 MB
    uint4*         Bf   = (uint4*)(ws + (2u << 20));            // 1.18 MB
    u32*           A1   = (u32*)(ws + (4u << 20));              // 2 MB
    u32*           A2   = (u32*)(ws + (6u << 20));              // 2 MB
    (void)ws_size; (void)in_sizes; (void)n_in; (void)out_size;

    prep_weights<<<dim3(256, 2), 256, 0, stream>>>(w1, w2, al1, g1, b1, m1, v1,
                                                   al2, g2, b2, m2, v2, Wsgn, SC4);
    build_bfrag<<<dim3(1152), 64, 0, stream>>>(Wsgn, Bf);
    binarize_x<<<dim3(512), 1024, 0, stream>>>(x, A1);
    conv_mfma<1><<<dim3(1024), 256, 0, stream>>>(A1, (const v4i*)Bf, SC4,
                                                 nullptr, A2, nullptr);
    conv_mfma<2><<<dim3(1024), 256, 0, stream>>>(A2, (const v4i*)Bf, SC4,
                                                 x, nullptr, out);
}

// Round 18
// 124.696 us; speedup vs baseline: 2.4904x; 1.1096x over previous
//
#include <hip/hip_runtime.h>
#include <cstdint>
#include <cstddef>

using u32 = unsigned int;
using u64 = unsigned long long;

typedef int v4i  __attribute__((ext_vector_type(4)));
typedef int v16i __attribute__((ext_vector_type(16)));

#define EPSV 1e-5f

// ---------------------------------------------------------------------------
// Kernel 1: weight prep. One block per (co, conv). 256 threads = 256 in-chans.
// Wsgn[conv][co][p][c] i8 = sign(w - mean); SC4 = (alpha, scale, shift, 0)
// with IEEE ops in the reference's exact order.
// ---------------------------------------------------------------------------
__global__ void prep_weights(const float* __restrict__ w1, const float* __restrict__ w2,
                             const float* __restrict__ a1, const float* __restrict__ g1,
                             const float* __restrict__ b1, const float* __restrict__ m1,
                             const float* __restrict__ v1,
                             const float* __restrict__ a2, const float* __restrict__ g2,
                             const float* __restrict__ b2, const float* __restrict__ m2,
                             const float* __restrict__ v2,
                             unsigned char* __restrict__ Wsgn, float4* __restrict__ SC4)
{
    const int co   = blockIdx.x;
    const int conv = blockIdx.y;
    const int c    = threadIdx.x;
    const float* w = conv ? w2 : w1;

    float wv[9];
    const float* wp = w + ((size_t)co * 256 + c) * 9;
    float s = 0.f;
#pragma unroll
    for (int p = 0; p < 9; ++p) { wv[p] = wp[p]; s += wv[p]; }

    __shared__ float red[256];
    red[c] = s;
    __syncthreads();
    for (int off = 128; off > 0; off >>= 1) {
        if (c < off) red[c] += red[c + off];
        __syncthreads();
    }
    const float mean = __fdiv_rn(red[0], 2304.0f);

    unsigned char* wrow = Wsgn + ((size_t)(conv * 256 + co) * 9) * 256;
#pragma unroll
    for (int p = 0; p < 9; ++p)
        wrow[p * 256 + c] = (wv[p] > mean) ? 0x01u : 0xFFu;

    if (c == 0) {
        const float alpha = conv ? a2[co] : a1[co];
        const float gamma = conv ? g2[co] : g1[co];
        const float beta  = conv ? b2[co] : b1[co];
        const float mu    = conv ? m2[co] : m1[co];
        const float var   = conv ? v2[co] : v1[co];
        const float sq    = __fsqrt_rn(__fadd_rn(var, EPSV));
        const float scale = __fdiv_rn(gamma, sq);
        const float shift = __fsub_rn(beta, __fdiv_rn(__fmul_rn(mu, gamma), sq));
        SC4[conv * 256 + co] = make_float4(alpha, scale, shift, 0.f);
    }
}

// ---------------------------------------------------------------------------
// Kernel 2: B fragments in exact mfma_i32_32x32x32_i8 operand order.
// Frag f = conv*576 + g*72 + p*8 + cb. Lane l: B[k=(l>>5)*16+j][n=l&31].
// ---------------------------------------------------------------------------
__global__ void build_bfrag(const unsigned char* __restrict__ Wsgn, uint4* __restrict__ Bf)
{
    const int f    = blockIdx.x;           // 0..1151
    const int lane = threadIdx.x;          // 0..63
    const int conv = f / 576;
    const int rem  = f % 576;
    const int g    = rem / 72;
    const int p    = (rem % 72) / 8;
    const int cb   = rem % 8;
    const int co   = g * 32 + (lane & 31);
    const unsigned char* src = Wsgn + ((size_t)(conv * 256 + co) * 9 + p) * 256
                                    + cb * 32 + (lane >> 5) * 16;
    Bf[(size_t)f * 64 + lane] = *(const uint4*)src;
}

// ---------------------------------------------------------------------------
// Kernel 3: binarize x -> packed bits. A[n][pixel][j], j = chan/32.
// ---------------------------------------------------------------------------
__global__ void binarize_x(const float* __restrict__ x, u32* __restrict__ A1)
{
    const int n = blockIdx.x >> 3;
    const int j = blockIdx.x & 7;
    const int p = threadIdx.x;
    const float* xp = x + (((size_t)n * 256 + j * 32) * 1024) + p;
    u32 bits = 0;
#pragma unroll
    for (int k = 0; k < 32; ++k) {
        float v = xp[(size_t)k * 1024];
        bits |= (v > 0.f ? 1u : 0u) << k;
    }
    A1[((size_t)n * 1024 + p) * 8 + j] = bits;
}

__device__ __forceinline__ u32 expand4(u32 x)
{
    u32 r;
    r  = ((x & 1u) ? 0x00000001u : 0x000000FFu);
    r |= ((x & 2u) ? 0x00000100u : 0x0000FF00u);
    r |= ((x & 4u) ? 0x00010000u : 0x00FF0000u);
    r |= ((x & 8u) ? 0x01000000u : 0xFF000000u);
    return r;
}

// ---------------------------------------------------------------------------
// Kernel 4/5: binary conv as i8 MFMA GEMM — R12 config (series best: 62us/conv)
// + bijective XCD swizzle (T1).
//
// Series post-mortem (R5-R17): nine spill-free schedules (lockstep barriers,
// serial rolled, SSA-dbuf, SB-pinned pipelines, 4-deep B regs, barrier-free
// rings, 8-phase counted-vmcnt, 1-wave ILP, 4-wave occupancy) ALL land at
// 60-74us/conv, MfmaUtil 21-25%. Per-step audit: ~1,800cyc/step of per-wave
// stall that neither prefetch depth, barrier discipline, LDS-read volume
// (varied 4x), nor occupancy hints move. Banking the best config.
//
// Block: 256 thr = 4 waves; M=128 (4 rows x 32 cols), N=256 (all couts).
// Wave w: groups g0=2w,g1=2w+1 x 4 rows -> 8 v16i accs (128 AGPR).
// Grid 512; swizzled so each XCD gets 64 consecutive logical blocks
// (8 whole images): logical = (wgid%8)*64 + wgid/8 (512%8==0 -> bijective).
//
// LDS act tile [c16 16][r 0..5][xs 0..34), 16B cells = 52,224 B.
// granule%8 = xs%8 -> ds_read_b128 conflict-free (R6-R17: 0 conflicts).
// Step k (0..71): cb=k&7, p=k>>3 (dy=p/3,dx=p%3);
//   dso = labase + cb*6528 + dy*544 + dx*16; rows at +0/544/1088/1632.
// B: 4 named register pairs cycle refill-after-use (~3 steps of cover);
// A: 1-step-ahead double buffer; SB-fenced phases; setprio on MFMA cluster.
// B-refill overrun at k4=17 lands in the mapped ws gap after Bf.
//
// A: m(=x)=l&31, k=(l>>5)*16+j ; B: n(=co)=l&31 ; C/D: n=l&31,
// m=(reg&3)+8*(reg>>2)+4*(l>>5)   [R5-R17 HW-verified].
//
// CONV==1: t=(dot*alpha)*scale+shift; packed sign bits via __ballot.
// CONV==2: per-row LDS transpose ep[x][co] (pad 257) -> coalesced
//          clamp(t + X) float4 stores.
// ---------------------------------------------------------------------------
template<int CONV>
__global__ __launch_bounds__(256, 2)
void conv_mfma(const u32* __restrict__ A_in, const v4i* __restrict__ Bf,
               const float4* __restrict__ SC4, const float* __restrict__ X,
               u32* __restrict__ A_out, float* __restrict__ OUT)
{
    // bijective XCD swizzle: XCD = wgid%8 gets logical blocks (wgid%8)*64 ..
    const int logical = (blockIdx.x & 7) * 64 + (blockIdx.x >> 3);
    const int n    = logical >> 3;
    const int yq   = logical & 7;
    const int y0   = yq * 4;
    const int tid  = threadIdx.x;
    const int wave = tid >> 6;
    const int lane = tid & 63;

    __shared__ alignas(16) unsigned char lds[52224];

    const int g0 = wave * 2, g1 = g0 + 1;
    const v4i* bp0 = Bf + ((size_t)(((CONV == 2) ? 576 : 0) + g0 * 72)) * 64 + lane;
    const v4i* bp1 = Bf + ((size_t)(((CONV == 2) ? 576 : 0) + g1 * 72)) * 64 + lane;

    // prologue B loads issued BEFORE staging (independent of LDS)
    v4i w00 = bp0[0],   w10 = bp1[0];
    v4i w01 = bp0[64],  w11 = bp1[64];
    v4i w02 = bp0[128], w12 = bp1[128];
    v4i w03 = bp0[192], w13 = bp1[192];

    // ---- stage: packed bits -> i8 tile [c16][r 0..5][xs], halo -> 0 ----
    for (int s = tid; s < 3264; s += 256) {
        const int xs   = s % 34;
        const int rest = s / 34;
        const int r    = rest % 6;          // tile row (image row y0-1+r)
        const int c16  = rest / 6;          // 16-channel group
        const int iy   = y0 - 1 + r;
        const int ix   = xs - 1;
        u32 d0 = 0, d1 = 0, d2 = 0, d3 = 0;
        if ((unsigned)iy < 32u && (unsigned)ix < 32u) {
            const u32 wrd = A_in[((size_t)n * 1024 + iy * 32 + ix) * 8 + (c16 >> 1)];
            const u32 h = (wrd >> ((c16 & 1) * 16)) & 0xFFFFu;
            d0 = expand4(h);
            d1 = expand4(h >> 4);
            d2 = expand4(h >> 8);
            d3 = expand4(h >> 12);
        }
        *(uint4*)(lds + ((size_t)((c16 * 6 + r) * 34 + xs)) * 16) =
            make_uint4(d0, d1, d2, d3);
    }
    __syncthreads();

    const v16i Z  = {0,0,0,0,0,0,0,0,0,0,0,0,0,0,0,0};
    const v4i  Z4 = {0,0,0,0};
    v16i acc00 = Z, acc01 = Z;   // row y0   x {g0,g1}
    v16i acc10 = Z, acc11 = Z;   // row y0+1
    v16i acc20 = Z, acc21 = Z;   // row y0+2
    v16i acc30 = Z, acc31 = Z;   // row y0+3

    const u32 labase = (u32)((lane >> 5) * 3264 + (lane & 31) * 16);

#define SB  __builtin_amdgcn_sched_barrier(0)

#define DSOFFK(K)                                                               \
    (labase + (u32)(((K) & 7) * 6528 + ((((K) >> 3)) / 3) * 544                 \
                    + ((((K) >> 3)) % 3) * 16))

#define PREFA(A0, A1, A2, A3, DSO)                                              \
    A0 = *(const v4i*)(lds + (DSO));                                            \
    A1 = *(const v4i*)(lds + (DSO) + 544);                                      \
    A2 = *(const v4i*)(lds + (DSO) + 1088);                                     \
    A3 = *(const v4i*)(lds + (DSO) + 1632);

#define MFMA8(A0, A1, A2, A3, W0, W1)                                           \
    acc00 = __builtin_amdgcn_mfma_i32_32x32x32_i8(A0, W0, acc00, 0, 0, 0);      \
    acc01 = __builtin_amdgcn_mfma_i32_32x32x32_i8(A0, W1, acc01, 0, 0, 0);      \
    acc10 = __builtin_amdgcn_mfma_i32_32x32x32_i8(A1, W0, acc10, 0, 0, 0);      \
    acc11 = __builtin_amdgcn_mfma_i32_32x32x32_i8(A1, W1, acc11, 0, 0, 0);      \
    acc20 = __builtin_amdgcn_mfma_i32_32x32x32_i8(A2, W0, acc20, 0, 0, 0);      \
    acc21 = __builtin_amdgcn_mfma_i32_32x32x32_i8(A2, W1, acc21, 0, 0, 0);      \
    acc30 = __builtin_amdgcn_mfma_i32_32x32x32_i8(A3, W0, acc30, 0, 0, 0);      \
    acc31 = __builtin_amdgcn_mfma_i32_32x32x32_i8(A3, W1, acc31, 0, 0, 0);

    // A double-buffer sets
    v4i ea0 = Z4, ea1 = Z4, ea2 = Z4, ea3 = Z4;
    v4i oa0 = Z4, oa1 = Z4, oa2 = Z4, oa3 = Z4;

    PREFA(ea0, ea1, ea2, ea3, DSOFFK(0))

#pragma unroll 1
    for (int k4 = 0; k4 < 18; ++k4) {
        const int kb = k4 * 4;
        // step 0: compute E/W0, prefetch A(kb+1)->O, refill W0<-frag kb+4
        PREFA(oa0, oa1, oa2, oa3, DSOFFK(kb + 1)) SB;
        __builtin_amdgcn_s_setprio(1);
        MFMA8(ea0, ea1, ea2, ea3, w00, w10)
        __builtin_amdgcn_s_setprio(0); SB;
        w00 = bp0[4 * 64]; w10 = bp1[4 * 64]; SB;
        // step 1: compute O/W1, prefetch A(kb+2)->E, refill W1<-frag kb+5
        PREFA(ea0, ea1, ea2, ea3, DSOFFK(kb + 2)) SB;
        __builtin_amdgcn_s_setprio(1);
        MFMA8(oa0, oa1, oa2, oa3, w01, w11)
        __builtin_amdgcn_s_setprio(0); SB;
        w01 = bp0[5 * 64]; w11 = bp1[5 * 64]; SB;
        // step 2: compute E/W2, prefetch A(kb+3)->O, refill W2<-frag kb+6
        PREFA(oa0, oa1, oa2, oa3, DSOFFK(kb + 3)) SB;
        __builtin_amdgcn_s_setprio(1);
        MFMA8(ea0, ea1, ea2, ea3, w02, w12)
        __builtin_amdgcn_s_setprio(0); SB;
        w02 = bp0[6 * 64]; w12 = bp1[6 * 64]; SB;
        // step 3: compute O/W3, prefetch A(kb+4)->E, refill W3<-frag kb+7
        PREFA(ea0, ea1, ea2, ea3, DSOFFK(kb + 4)) SB;
        __builtin_amdgcn_s_setprio(1);
        MFMA8(oa0, oa1, oa2, oa3, w03, w13)
        __builtin_amdgcn_s_setprio(0); SB;
        w03 = bp0[7 * 64]; w13 = bp1[7 * 64]; SB;

        bp0 += 256; bp1 += 256;
    }
#undef DSOFFK
#undef PREFA
#undef MFMA8
#undef SB

    const int col = lane & 31;
    const float4 sc0 = SC4[((CONV == 2) ? 256 : 0) + g0 * 32 + col];
    const float4 sc1 = SC4[((CONV == 2) ? 256 : 0) + g1 * 32 + col];

    if (CONV == 1) {
#define EP1(ACC, RY, G, SC)                                                     \
        { _Pragma("unroll")                                                     \
          for (int reg = 0; reg < 16; ++reg) {                                  \
              const float t = __fadd_rn(__fmul_rn(__fmul_rn((float)ACC[reg],    \
                                        SC.x), SC.y), SC.z);                    \
              const u64 m = __ballot(t > 0.f);                                  \
              if (lane == 0) {                                                  \
                  const int x = (reg & 3) + 8 * (reg >> 2);                     \
                  const size_t pb = (size_t)n * 1024 + (y0 + (RY)) * 32 + x;    \
                  A_out[pb * 8 + (G)]       = (u32)m;                           \
                  A_out[(pb + 4) * 8 + (G)] = (u32)(m >> 32);                   \
              } } }
        EP1(acc00, 0, g0, sc0)  EP1(acc01, 0, g1, sc1)
        EP1(acc10, 1, g0, sc0)  EP1(acc11, 1, g1, sc1)
        EP1(acc20, 2, g0, sc0)  EP1(acc21, 2, g1, sc1)
        EP1(acc30, 3, g0, sc0)  EP1(acc31, 3, g1, sc1)
#undef EP1
    } else {
        __syncthreads();                    // act tile reads done
        float* ep = (float*)lds;            // ep[x][co] pad 257 = 32.9 KB
#define EP2PASS(A0, A1, RY)                                                     \
        { _Pragma("unroll")                                                     \
          for (int reg = 0; reg < 16; ++reg) {                                  \
              const int x = (reg & 3) + 8 * (reg >> 2) + 4 * (lane >> 5);       \
              const float t0 = __fadd_rn(__fmul_rn(__fmul_rn((float)A0[reg],    \
                                         sc0.x), sc0.y), sc0.z);                \
              const float t1 = __fadd_rn(__fmul_rn(__fmul_rn((float)A1[reg],    \
                                         sc1.x), sc1.y), sc1.z);                \
              ep[x * 257 + g0 * 32 + col] = t0;                                 \
              ep[x * 257 + g1 * 32 + col] = t1;                                 \
          }                                                                     \
          __syncthreads();                                                      \
          {                                                                     \
              const int co = tid;                                               \
              const size_t gb = ((size_t)(n * 256 + co)) * 1024                 \
                              + (y0 + (RY)) * 32;                               \
              _Pragma("unroll")                                                 \
              for (int x4 = 0; x4 < 32; x4 += 4) {                              \
                  float4 r;                                                     \
                  r.x = ep[(x4 + 0) * 257 + co];                                \
                  r.y = ep[(x4 + 1) * 257 + co];                                \
                  r.z = ep[(x4 + 2) * 257 + co];                                \
                  r.w = ep[(x4 + 3) * 257 + co];                                \
                  const float4 xv = *(const float4*)(X + gb + x4);              \
                  r.x = fminf(1.f, fmaxf(-1.f, __fadd_rn(r.x, xv.x)));          \
                  r.y = fminf(1.f, fmaxf(-1.f, __fadd_rn(r.y, xv.y)));          \
                  r.z = fminf(1.f, fmaxf(-1.f, __fadd_rn(r.z, xv.z)));          \
                  r.w = fminf(1.f, fmaxf(-1.f, __fadd_rn(r.w, xv.w)));          \
                  *(float4*)(OUT + gb + x4) = r;                                \
              }                                                                 \
          }                                                                     \
          __syncthreads(); }
        EP2PASS(acc00, acc01, 0)
        EP2PASS(acc10, acc11, 1)
        EP2PASS(acc20, acc21, 2)
        EP2PASS(acc30, acc31, 3)
#undef EP2PASS
    }
}

// ---------------------------------------------------------------------------
extern "C" void kernel_launch(void* const* d_in, const int* in_sizes, int n_in,
                              void* d_out, int out_size, void* d_ws, size_t ws_size,
                              hipStream_t stream)
{
    const float* x   = (const float*)d_in[0];
    const float* w1  = (const float*)d_in[1];
    const float* al1 = (const float*)d_in[2];
    const float* g1  = (const float*)d_in[3];
    const float* b1  = (const float*)d_in[4];
    const float* m1  = (const float*)d_in[5];
    const float* v1  = (const float*)d_in[6];
    const float* w2  = (const float*)d_in[7];
    const float* al2 = (const float*)d_in[8];
    const float* g2  = (const float*)d_in[9];
    const float* b2  = (const float*)d_in[10];
    const float* m2  = (const float*)d_in[11];
    const float* v2  = (const float*)d_in[12];
    float* out = (float*)d_out;

    char* ws = (char*)d_ws;
    float4*        SC4  = (float4*)(ws);                        //   8 KB
    unsigned char* Wsgn = (unsigned char*)(ws + (64u << 10));   // 1.18 MB
    uint4*         Bf   = (uint4*)(ws + (2u << 20));            // 1.18 MB (+overrun gap)
    u32*           A1   = (u32*)(ws + (4u << 20));              // 2 MB
    u32*           A2   = (u32*)(ws + (6u << 20));              // 2 MB
    (void)ws_size; (void)in_sizes; (void)n_in; (void)out_size;

    prep_weights<<<dim3(256, 2), 256, 0, stream>>>(w1, w2, al1, g1, b1, m1, v1,
                                                   al2, g2, b2, m2, v2, Wsgn, SC4);
    build_bfrag<<<dim3(1152), 64, 0, stream>>>(Wsgn, Bf);
    binarize_x<<<dim3(512), 1024, 0, stream>>>(x, A1);
    conv_mfma<1><<<dim3(512), 256, 0, stream>>>(A1, (const v4i*)Bf, SC4,
                                                nullptr, A2, nullptr);
    conv_mfma<2><<<dim3(512), 256, 0, stream>>>(A2, (const v4i*)Bf, SC4,
                                                x, nullptr, out);
}

// Round 19
// 123.586 us; speedup vs baseline: 2.5128x; 1.0090x over previous
//
#include <hip/hip_runtime.h>
#include <cstdint>
#include <cstddef>

using u32 = unsigned int;
using u64 = unsigned long long;

typedef int v4i  __attribute__((ext_vector_type(4)));
typedef int v16i __attribute__((ext_vector_type(16)));

#define EPSV 1e-5f

// ---------------------------------------------------------------------------
// Kernel 1: weight prep. One block per (co, conv). 256 threads = 256 in-chans.
// Wsgn[conv][co][p][c] i8 = sign(w - mean); SC4 = (alpha, scale, shift, 0)
// with IEEE ops in the reference's exact order.
// ---------------------------------------------------------------------------
__global__ void prep_weights(const float* __restrict__ w1, const float* __restrict__ w2,
                             const float* __restrict__ a1, const float* __restrict__ g1,
                             const float* __restrict__ b1, const float* __restrict__ m1,
                             const float* __restrict__ v1,
                             const float* __restrict__ a2, const float* __restrict__ g2,
                             const float* __restrict__ b2, const float* __restrict__ m2,
                             const float* __restrict__ v2,
                             unsigned char* __restrict__ Wsgn, float4* __restrict__ SC4)
{
    const int co   = blockIdx.x;
    const int conv = blockIdx.y;
    const int c    = threadIdx.x;
    const float* w = conv ? w2 : w1;

    float wv[9];
    const float* wp = w + ((size_t)co * 256 + c) * 9;
    float s = 0.f;
#pragma unroll
    for (int p = 0; p < 9; ++p) { wv[p] = wp[p]; s += wv[p]; }

    __shared__ float red[256];
    red[c] = s;
    __syncthreads();
    for (int off = 128; off > 0; off >>= 1) {
        if (c < off) red[c] += red[c + off];
        __syncthreads();
    }
    const float mean = __fdiv_rn(red[0], 2304.0f);

    unsigned char* wrow = Wsgn + ((size_t)(conv * 256 + co) * 9) * 256;
#pragma unroll
    for (int p = 0; p < 9; ++p)
        wrow[p * 256 + c] = (wv[p] > mean) ? 0x01u : 0xFFu;

    if (c == 0) {
        const float alpha = conv ? a2[co] : a1[co];
        const float gamma = conv ? g2[co] : g1[co];
        const float beta  = conv ? b2[co] : b1[co];
        const float mu    = conv ? m2[co] : m1[co];
        const float var   = conv ? v2[co] : v1[co];
        const float sq    = __fsqrt_rn(__fadd_rn(var, EPSV));
        const float scale = __fdiv_rn(gamma, sq);
        const float shift = __fsub_rn(beta, __fdiv_rn(__fmul_rn(mu, gamma), sq));
        SC4[conv * 256 + co] = make_float4(alpha, scale, shift, 0.f);
    }
}

// ---------------------------------------------------------------------------
// Kernel 2: B fragments in exact mfma_i32_32x32x32_i8 operand order.
// Frag f = conv*576 + g*72 + p*8 + cb. Lane l: B[k=(l>>5)*16+j][n=l&31].
// ---------------------------------------------------------------------------
__global__ void build_bfrag(const unsigned char* __restrict__ Wsgn, uint4* __restrict__ Bf)
{
    const int f    = blockIdx.x;           // 0..1151
    const int lane = threadIdx.x;          // 0..63
    const int conv = f / 576;
    const int rem  = f % 576;
    const int g    = rem / 72;
    const int p    = (rem % 72) / 8;
    const int cb   = rem % 8;
    const int co   = g * 32 + (lane & 31);
    const unsigned char* src = Wsgn + ((size_t)(conv * 256 + co) * 9 + p) * 256
                                    + cb * 32 + (lane >> 5) * 16;
    Bf[(size_t)f * 64 + lane] = *(const uint4*)src;
}

// ---------------------------------------------------------------------------
// Kernel 3: binarize x -> packed bits. A[n][pixel][j], j = chan/32.
// ---------------------------------------------------------------------------
__global__ void binarize_x(const float* __restrict__ x, u32* __restrict__ A1)
{
    const int n = blockIdx.x >> 3;
    const int j = blockIdx.x & 7;
    const int p = threadIdx.x;
    const float* xp = x + (((size_t)n * 256 + j * 32) * 1024) + p;
    u32 bits = 0;
#pragma unroll
    for (int k = 0; k < 32; ++k) {
        float v = xp[(size_t)k * 1024];
        bits |= (v > 0.f ? 1u : 0u) << k;
    }
    A1[((size_t)n * 1024 + p) * 8 + j] = bits;
}

__device__ __forceinline__ u32 expand4(u32 x)
{
    u32 r;
    r  = ((x & 1u) ? 0x00000001u : 0x000000FFu);
    r |= ((x & 2u) ? 0x00000100u : 0x0000FF00u);
    r |= ((x & 4u) ? 0x00010000u : 0x00FF0000u);
    r |= ((x & 8u) ? 0x01000000u : 0xFF000000u);
    return r;
}

// ---------------------------------------------------------------------------
// Kernel 4/5: binary conv as i8 MFMA GEMM — R18 config, leaner pinning.
//
// Changes vs R18 (A/B, both low-risk): (1) s_setprio removed — m190 analog
// (homogeneous barrier-less GEMM waves) shows null-to-negative; (2) B-refill
// hoisted into the NEXT step's load region (refill W[(k-1)&3] <- frag k+3
// before PREFA): 2 sched_barriers/step instead of 3, each B load issued one
// MFMA-cluster earlier. Ordering safe: each W-pair is consumed by the prior
// step's cluster BEFORE its refill in program order; cover stays 3 steps.
//
// Block: 256 thr = 4 waves; M=128 (4 rows x 32 cols), N=256 (all couts).
// Wave w: groups g0=2w,g1=2w+1 x 4 rows -> 8 v16i accs (128 AGPR).
// Grid 512; bijective XCD swizzle: logical = (wgid%8)*64 + wgid/8.
//
// LDS act tile [c16 16][r 0..5][xs 0..34), 16B cells = 52,224 B.
// granule%8 = xs%8 -> ds_read_b128 conflict-free (R6-R18: 0 conflicts).
// Step k (0..71): cb=k&7, p=k>>3 (dy=p/3,dx=p%3);
//   dso = labase + cb*6528 + dy*544 + dx*16; rows at +0/544/1088/1632.
// B: 4 named register pairs, refill-3-ahead; A: 1-step double buffer.
// Tail overruns land in mapped ws (never consumed).
//
// A: m(=x)=l&31, k=(l>>5)*16+j ; B: n(=co)=l&31 ; C/D: n=l&31,
// m=(reg&3)+8*(reg>>2)+4*(l>>5)   [R5-R18 HW-verified].
//
// CONV==1: t=(dot*alpha)*scale+shift; packed sign bits via __ballot.
// CONV==2: per-row LDS transpose ep[x][co] (pad 257) -> coalesced
//          clamp(t + X) float4 stores.
// ---------------------------------------------------------------------------
template<int CONV>
__global__ __launch_bounds__(256, 2)
void conv_mfma(const u32* __restrict__ A_in, const v4i* __restrict__ Bf,
               const float4* __restrict__ SC4, const float* __restrict__ X,
               u32* __restrict__ A_out, float* __restrict__ OUT)
{
    // bijective XCD swizzle: XCD = wgid%8 gets 64 consecutive logical blocks
    const int logical = (blockIdx.x & 7) * 64 + (blockIdx.x >> 3);
    const int n    = logical >> 3;
    const int yq   = logical & 7;
    const int y0   = yq * 4;
    const int tid  = threadIdx.x;
    const int wave = tid >> 6;
    const int lane = tid & 63;

    __shared__ alignas(16) unsigned char lds[52224];

    const int g0 = wave * 2, g1 = g0 + 1;
    const v4i* bp0 = Bf + ((size_t)(((CONV == 2) ? 576 : 0) + g0 * 72)) * 64 + lane;
    const v4i* bp1 = Bf + ((size_t)(((CONV == 2) ? 576 : 0) + g1 * 72)) * 64 + lane;

    // prologue B loads issued BEFORE staging (frags 0..2; W3 filled in-loop)
    v4i w00 = bp0[0],   w10 = bp1[0];
    v4i w01 = bp0[64],  w11 = bp1[64];
    v4i w02 = bp0[128], w12 = bp1[128];
    v4i w03 = w02,      w13 = w12;      // placeholder; refilled at step 0

    // ---- stage: packed bits -> i8 tile [c16][r 0..5][xs], halo -> 0 ----
    for (int s = tid; s < 3264; s += 256) {
        const int xs   = s % 34;
        const int rest = s / 34;
        const int r    = rest % 6;          // tile row (image row y0-1+r)
        const int c16  = rest / 6;          // 16-channel group
        const int iy   = y0 - 1 + r;
        const int ix   = xs - 1;
        u32 d0 = 0, d1 = 0, d2 = 0, d3 = 0;
        if ((unsigned)iy < 32u && (unsigned)ix < 32u) {
            const u32 wrd = A_in[((size_t)n * 1024 + iy * 32 + ix) * 8 + (c16 >> 1)];
            const u32 h = (wrd >> ((c16 & 1) * 16)) & 0xFFFFu;
            d0 = expand4(h);
            d1 = expand4(h >> 4);
            d2 = expand4(h >> 8);
            d3 = expand4(h >> 12);
        }
        *(uint4*)(lds + ((size_t)((c16 * 6 + r) * 34 + xs)) * 16) =
            make_uint4(d0, d1, d2, d3);
    }
    __syncthreads();

    const v16i Z  = {0,0,0,0,0,0,0,0,0,0,0,0,0,0,0,0};
    const v4i  Z4 = {0,0,0,0};
    v16i acc00 = Z, acc01 = Z;   // row y0   x {g0,g1}
    v16i acc10 = Z, acc11 = Z;   // row y0+1
    v16i acc20 = Z, acc21 = Z;   // row y0+2
    v16i acc30 = Z, acc31 = Z;   // row y0+3

    const u32 labase = (u32)((lane >> 5) * 3264 + (lane & 31) * 16);

#define SB  __builtin_amdgcn_sched_barrier(0)

#define DSOFFK(K)                                                               \
    (labase + (u32)(((K) & 7) * 6528 + ((((K) >> 3)) / 3) * 544                 \
                    + ((((K) >> 3)) % 3) * 16))

#define PREFA(A0, A1, A2, A3, DSO)                                              \
    A0 = *(const v4i*)(lds + (DSO));                                            \
    A1 = *(const v4i*)(lds + (DSO) + 544);                                      \
    A2 = *(const v4i*)(lds + (DSO) + 1088);                                     \
    A3 = *(const v4i*)(lds + (DSO) + 1632);

#define MFMA8(A0, A1, A2, A3, W0, W1)                                           \
    acc00 = __builtin_amdgcn_mfma_i32_32x32x32_i8(A0, W0, acc00, 0, 0, 0);      \
    acc01 = __builtin_amdgcn_mfma_i32_32x32x32_i8(A0, W1, acc01, 0, 0, 0);      \
    acc10 = __builtin_amdgcn_mfma_i32_32x32x32_i8(A1, W0, acc10, 0, 0, 0);      \
    acc11 = __builtin_amdgcn_mfma_i32_32x32x32_i8(A1, W1, acc11, 0, 0, 0);      \
    acc20 = __builtin_amdgcn_mfma_i32_32x32x32_i8(A2, W0, acc20, 0, 0, 0);      \
    acc21 = __builtin_amdgcn_mfma_i32_32x32x32_i8(A2, W1, acc21, 0, 0, 0);      \
    acc30 = __builtin_amdgcn_mfma_i32_32x32x32_i8(A3, W0, acc30, 0, 0, 0);      \
    acc31 = __builtin_amdgcn_mfma_i32_32x32x32_i8(A3, W1, acc31, 0, 0, 0);

    // A double-buffer sets
    v4i ea0 = Z4, ea1 = Z4, ea2 = Z4, ea3 = Z4;
    v4i oa0 = Z4, oa1 = Z4, oa2 = Z4, oa3 = Z4;

    PREFA(ea0, ea1, ea2, ea3, DSOFFK(0))

#pragma unroll 1
    for (int k4 = 0; k4 < 18; ++k4) {
        const int kb = k4 * 4;
        // step 0: refill W3<-frag kb+3 ; prefetch A(kb+1)->O ; MFMA E/W0
        w03 = bp0[3 * 64]; w13 = bp1[3 * 64];
        PREFA(oa0, oa1, oa2, oa3, DSOFFK(kb + 1)) SB;
        MFMA8(ea0, ea1, ea2, ea3, w00, w10) SB;
        // step 1: refill W0<-frag kb+4 ; prefetch A(kb+2)->E ; MFMA O/W1
        w00 = bp0[4 * 64]; w10 = bp1[4 * 64];
        PREFA(ea0, ea1, ea2, ea3, DSOFFK(kb + 2)) SB;
        MFMA8(oa0, oa1, oa2, oa3, w01, w11) SB;
        // step 2: refill W1<-frag kb+5 ; prefetch A(kb+3)->O ; MFMA E/W2
        w01 = bp0[5 * 64]; w11 = bp1[5 * 64];
        PREFA(oa0, oa1, oa2, oa3, DSOFFK(kb + 3)) SB;
        MFMA8(ea0, ea1, ea2, ea3, w02, w12) SB;
        // step 3: refill W2<-frag kb+6 ; prefetch A(kb+4)->E ; MFMA O/W3
        w02 = bp0[6 * 64]; w12 = bp1[6 * 64];
        PREFA(ea0, ea1, ea2, ea3, DSOFFK(kb + 4)) SB;
        MFMA8(oa0, oa1, oa2, oa3, w03, w13) SB;

        bp0 += 256; bp1 += 256;
    }
#undef DSOFFK
#undef PREFA
#undef MFMA8
#undef SB

    const int col = lane & 31;
    const float4 sc0 = SC4[((CONV == 2) ? 256 : 0) + g0 * 32 + col];
    const float4 sc1 = SC4[((CONV == 2) ? 256 : 0) + g1 * 32 + col];

    if (CONV == 1) {
#define EP1(ACC, RY, G, SC)                                                     \
        { _Pragma("unroll")                                                     \
          for (int reg = 0; reg < 16; ++reg) {                                  \
              const float t = __fadd_rn(__fmul_rn(__fmul_rn((float)ACC[reg],    \
                                        SC.x), SC.y), SC.z);                    \
              const u64 m = __ballot(t > 0.f);                                  \
              if (lane == 0) {                                                  \
                  const int x = (reg & 3) + 8 * (reg >> 2);                     \
                  const size_t pb = (size_t)n * 1024 + (y0 + (RY)) * 32 + x;    \
                  A_out[pb * 8 + (G)]       = (u32)m;                           \
                  A_out[(pb + 4) * 8 + (G)] = (u32)(m >> 32);                   \
              } } }
        EP1(acc00, 0, g0, sc0)  EP1(acc01, 0, g1, sc1)
        EP1(acc10, 1, g0, sc0)  EP1(acc11, 1, g1, sc1)
        EP1(acc20, 2, g0, sc0)  EP1(acc21, 2, g1, sc1)
        EP1(acc30, 3, g0, sc0)  EP1(acc31, 3, g1, sc1)
#undef EP1
    } else {
        __syncthreads();                    // act tile reads done
        float* ep = (float*)lds;            // ep[x][co] pad 257 = 32.9 KB
#define EP2PASS(A0, A1, RY)                                                     \
        { _Pragma("unroll")                                                     \
          for (int reg = 0; reg < 16; ++reg) {                                  \
              const int x = (reg & 3) + 8 * (reg >> 2) + 4 * (lane >> 5);       \
              const float t0 = __fadd_rn(__fmul_rn(__fmul_rn((float)A0[reg],    \
                                         sc0.x), sc0.y), sc0.z);                \
              const float t1 = __fadd_rn(__fmul_rn(__fmul_rn((float)A1[reg],    \
                                         sc1.x), sc1.y), sc1.z);                \
              ep[x * 257 + g0 * 32 + col] = t0;                                 \
              ep[x * 257 + g1 * 32 + col] = t1;                                 \
          }                                                                     \
          __syncthreads();                                                      \
          {                                                                     \
              const int co = tid;                                               \
              const size_t gb = ((size_t)(n * 256 + co)) * 1024                 \
                              + (y0 + (RY)) * 32;                               \
              _Pragma("unroll")                                                 \
              for (int x4 = 0; x4 < 32; x4 += 4) {                              \
                  float4 r;                                                     \
                  r.x = ep[(x4 + 0) * 257 + co];                                \
                  r.y = ep[(x4 + 1) * 257 + co];                                \
                  r.z = ep[(x4 + 2) * 257 + co];                                \
                  r.w = ep[(x4 + 3) * 257 + co];                                \
                  const float4 xv = *(const float4*)(X + gb + x4);              \
                  r.x = fminf(1.f, fmaxf(-1.f, __fadd_rn(r.x, xv.x)));          \
                  r.y = fminf(1.f, fmaxf(-1.f, __fadd_rn(r.y, xv.y)));          \
                  r.z = fminf(1.f, fmaxf(-1.f, __fadd_rn(r.z, xv.z)));          \
                  r.w = fminf(1.f, fmaxf(-1.f, __fadd_rn(r.w, xv.w)));          \
                  *(float4*)(OUT + gb + x4) = r;                                \
              }                                                                 \
          }                                                                     \
          __syncthreads(); }
        EP2PASS(acc00, acc01, 0)
        EP2PASS(acc10, acc11, 1)
        EP2PASS(acc20, acc21, 2)
        EP2PASS(acc30, acc31, 3)
#undef EP2PASS
    }
}

// ---------------------------------------------------------------------------
extern "C" void kernel_launch(void* const* d_in, const int* in_sizes, int n_in,
                              void* d_out, int out_size, void* d_ws, size_t ws_size,
                              hipStream_t stream)
{
    const float* x   = (const float*)d_in[0];
    const float* w1  = (const float*)d_in[1];
    const float* al1 = (const float*)d_in[2];
    const float* g1  = (const float*)d_in[3];
    const float* b1  = (const float*)d_in[4];
    const float* m1  = (const float*)d_in[5];
    const float* v1  = (const float*)d_in[6];
    const float* w2  = (const float*)d_in[7];
    const float* al2 = (const float*)d_in[8];
    const float* g2  = (const float*)d_in[9];
    const float* b2  = (const float*)d_in[10];
    const float* m2  = (const float*)d_in[11];
    const float* v2  = (const float*)d_in[12];
    float* out = (float*)d_out;

    char* ws = (char*)d_ws;
    float4*        SC4  = (float4*)(ws);                        //   8 KB
    unsigned char* Wsgn = (unsigned char*)(ws + (64u << 10));   // 1.18 MB
    uint4*         Bf   = (uint4*)(ws + (2u << 20));            // 1.18 MB (+overrun gap)
    u32*           A1   = (u32*)(ws + (4u << 20));              // 2 MB
    u32*           A2   = (u32*)(ws + (6u << 20));              // 2 MB
    (void)ws_size; (void)in_sizes; (void)n_in; (void)out_size;

    prep_weights<<<dim3(256, 2), 256, 0, stream>>>(w1, w2, al1, g1, b1, m1, v1,
                                                   al2, g2, b2, m2, v2, Wsgn, SC4);
    build_bfrag<<<dim3(1152), 64, 0, stream>>>(Wsgn, Bf);
    binarize_x<<<dim3(512), 1024, 0, stream>>>(x, A1);
    conv_mfma<1><<<dim3(512), 256, 0, stream>>>(A1, (const v4i*)Bf, SC4,
                                                nullptr, A2, nullptr);
    conv_mfma<2><<<dim3(512), 256, 0, stream>>>(A2, (const v4i*)Bf, SC4,
                                                x, nullptr, out);
}